// Round 4
// baseline (1757.507 us; speedup 1.0000x reference)
//
#include <hip/hip_runtime.h>
#include <math.h>

#define B_ 4
#define N_ 1024
#define C_ 1024
#define H_ 16
#define HD_ 64

// ---------------------------------------------------------------------------
// ERROR MODEL (drives every precision choice below):
//   out row scale ~ num/S with S ~ 6.6e-6 at the worst row (cancellation of
//   64 head-dims). delta_S budget = 2%*S ~ 1.3e-7 (full 1/S amplification).
//   Numerator errors are DAMPED by W_proj (delta_out = 0.16*delta_a/S,
//   budget delta_a ~ 4e-3) -> PV / stored q,k,v can be plain f32.
//   S = (1-g)*sum_m pbar_m*V_m + g*sum_m qbar_m*V_m needs:
//     - V_m exact        -> computed in f64 straight from x (wsum collapse)
//     - pos weights f64  -> dist chain + exp in f64
//     - patch weights    -> expf ok (diffuse softmax damps eps*5*0.045*0.27)
//       but q,k must carry < ~1e-7 error -> slab-compensated GEMM.
// ---------------------------------------------------------------------------

// ---------------------------------------------------------------------------
// GEMM: out[m][o] = sum_k A[m][k] * Wrow(o)[k]  (+bias MODE 1)
// Tile 128x64, KT=16, 256 threads, 8x4/thread.
// f32 inner products per 16-term slab (partial sums stay ~0.05 -> tiny
// rounding), folded into f64 accumulators: delta(out_elem) ~ 1e-7.
// MODE 0: fused QKV, O=3072 (W_qk rows 0..2047 | W_v rows 0..1023),
//         scatter into q/k/v [B][H][N][64]. MODE 1: row-major + bias.
// ---------------------------------------------------------------------------
template<int MODE>
__global__ __launch_bounds__(256)
void gemm_kernel(const float* __restrict__ A,
                 const float* __restrict__ W0,
                 const float* __restrict__ W1,
                 const float* __restrict__ bias,
                 float* __restrict__ out0,
                 float* __restrict__ out1,
                 float* __restrict__ out2,
                 int M, int O, int K)
{
    __shared__ float As[16][132];   // [k][m], 128 wide, +4 pad
    __shared__ float Ws[16][68];    // [k][o], 64 wide, +4 pad

    const int t  = threadIdx.x;
    const int m0 = blockIdx.y * 128;
    const int o0 = blockIdx.x * 64;
    const int ty = t >> 4;    // 0..15 -> 8 rows each
    const int tx = t & 15;    // 0..15 -> 4 cols each

    double acc[8][4];
    #pragma unroll
    for (int i = 0; i < 8; ++i)
        #pragma unroll
        for (int j = 0; j < 4; ++j) acc[i][j] = 0.0;

    for (int k0 = 0; k0 < K; k0 += 16) {
        // stage A tile: 128 rows x 16 k
        #pragma unroll
        for (int i = 0; i < 2; ++i) {
            int vix = t + i * 256;
            int r   = vix >> 2;
            int c4  = vix & 3;
            const float4 a4 = *reinterpret_cast<const float4*>(&A[(size_t)(m0 + r) * K + k0 + c4 * 4]);
            As[c4 * 4 + 0][r] = a4.x;
            As[c4 * 4 + 1][r] = a4.y;
            As[c4 * 4 + 2][r] = a4.z;
            As[c4 * 4 + 3][r] = a4.w;
        }
        // stage W tile: 64 channels x 16 k
        {
            int c  = t >> 2;          // 0..63
            int c4 = t & 3;
            int o  = o0 + c;
            const float* wrow = (MODE == 0 && o >= 2048) ? (W1 + (size_t)(o - 2048) * K)
                                                         : (W0 + (size_t)o * K);
            const float4 w4 = *reinterpret_cast<const float4*>(&wrow[k0 + c4 * 4]);
            Ws[c4 * 4 + 0][c] = w4.x;
            Ws[c4 * 4 + 1][c] = w4.y;
            Ws[c4 * 4 + 2][c] = w4.z;
            Ws[c4 * 4 + 3][c] = w4.w;
        }
        __syncthreads();

        float sacc[8][4];
        #pragma unroll
        for (int i = 0; i < 8; ++i)
            #pragma unroll
            for (int j = 0; j < 4; ++j) sacc[i][j] = 0.f;

        #pragma unroll
        for (int kk = 0; kk < 16; ++kk) {
            float a[8], bb[4];
            *reinterpret_cast<float4*>(&a[0])  = *reinterpret_cast<const float4*>(&As[kk][ty * 8]);
            *reinterpret_cast<float4*>(&a[4])  = *reinterpret_cast<const float4*>(&As[kk][ty * 8 + 4]);
            *reinterpret_cast<float4*>(&bb[0]) = *reinterpret_cast<const float4*>(&Ws[kk][tx * 4]);
            #pragma unroll
            for (int i = 0; i < 8; ++i)
                #pragma unroll
                for (int j = 0; j < 4; ++j)
                    sacc[i][j] += a[i] * bb[j];
        }
        // fold slab into f64
        #pragma unroll
        for (int i = 0; i < 8; ++i)
            #pragma unroll
            for (int j = 0; j < 4; ++j) acc[i][j] += (double)sacc[i][j];
        __syncthreads();
    }

    if (MODE == 1) {
        const float4 bsv = *reinterpret_cast<const float4*>(&bias[o0 + tx * 4]);
        #pragma unroll
        for (int i = 0; i < 8; ++i) {
            int m = m0 + ty * 8 + i;
            float4 r0 = make_float4((float)acc[i][0] + bsv.x, (float)acc[i][1] + bsv.y,
                                    (float)acc[i][2] + bsv.z, (float)acc[i][3] + bsv.w);
            *reinterpret_cast<float4*>(&out0[(size_t)m * O + o0 + tx * 4]) = r0;
        }
    } else {
        int oo = o0 + tx * 4;     // 4-aligned, single head
        float* dst;
        if (oo < 2048) { dst = (oo < 1024) ? out0 : out1; oo &= 1023; }
        else           { dst = out2; oo -= 2048; }
        int hh = oo >> 6, d0 = oo & 63;
        #pragma unroll
        for (int i = 0; i < 8; ++i) {
            int m = m0 + ty * 8 + i;
            int bb_ = m >> 10, n = m & 1023;
            float4 r0 = make_float4((float)acc[i][0], (float)acc[i][1],
                                    (float)acc[i][2], (float)acc[i][3]);
            *reinterpret_cast<float4*>(&dst[((((size_t)bb_ * H_) + hh) * N_ + n) * HD_ + d0]) = r0;
        }
    }
}

// ---------------------------------------------------------------------------
// wsum[h][k] = sum_{d in head h} W_v[h*64+d][k]   (f64)
// ---------------------------------------------------------------------------
__global__ void wsum_kernel(const float* __restrict__ W_v, double* __restrict__ wsh)
{
    const int k = blockIdx.x * 256 + threadIdx.x;   // grid.x = 4
    const int h = blockIdx.y;
    double s = 0.0;
    #pragma unroll 8
    for (int d = 0; d < 64; ++d) s += (double)W_v[(size_t)(h * 64 + d) * C_ + k];
    wsh[h * C_ + k] = s;
}

// ---------------------------------------------------------------------------
// Vall[b][h][m] = x[b,m,:] . wsum[h,:]  (f64)  == exact sum_d v[b,h,m,d]
// This bypasses the f32 v-GEMM for the S path entirely.
// ---------------------------------------------------------------------------
__global__ __launch_bounds__(256)
void vall_kernel(const float* __restrict__ x, const double* __restrict__ wsh,
                 double* __restrict__ Vall)
{
    __shared__ double ws_s[1024];
    const int h = blockIdx.y, b = blockIdx.z;
    const int m = blockIdx.x * 256 + threadIdx.x;   // grid.x = 4
    for (int i = threadIdx.x; i < 1024; i += 256) ws_s[i] = wsh[h * C_ + i];
    __syncthreads();
    const float* xr = x + ((size_t)b * N_ + m) * C_;
    double acc = 0.0;
    #pragma unroll 8
    for (int kk = 0; kk < 1024; ++kk) acc += (double)xr[kk] * ws_s[kk];
    Vall[((size_t)b * H_ + h) * N_ + m] = acc;
}

// ---------------------------------------------------------------------------
// Fused attention. Per block = (b, h, 16 q-rows); 64-row K/V tiles.
// Shift-free exact softmax (logits bounded ~|3|,|5.5| -> exp safe unshifted).
// S path: f64 weights x exact f64 V_m. PV numerators f32 (damped, see model).
// pos_logits terms constant in m (pe.W_pos[:3]+b_pos) cancel in softmax.
// ---------------------------------------------------------------------------
__global__ __launch_bounds__(256)
void attn_kernel(const float* __restrict__ q,
                 const float* __restrict__ k,
                 const float* __restrict__ v,
                 const double* __restrict__ Vall,   // [B][H][N]
                 const float* __restrict__ coord,   // [B][N][3]
                 const float* __restrict__ W_pos,   // [H][4]
                 const float* __restrict__ gating,  // [H]
                 float* __restrict__ attn_out)      // [B][N][C]
{
    __shared__ float4 Qs4[16][16];     // q rows [r][d4]
    __shared__ float4 Kt4[64][16];     // swizzled K tile
    __shared__ float4 Vt4[64][16];     // swizzled V tile
    __shared__ __align__(16) float pt[16][64];   // patch weights (tile)
    __shared__ __align__(16) float qt[16][64];   // pos weights (tile)
    __shared__ float qc[16][3];

    const int t  = threadIdx.x;
    const int w  = t >> 6;     // wave 0..3
    const int l  = t & 63;     // lane
    const int n0 = blockIdx.x * 16;
    const int h  = blockIdx.y;
    const int b  = blockIdx.z;

    const float* qbase = q + (((size_t)b * H_ + h) * N_ + n0) * HD_;
    Qs4[t >> 4][t & 15] = reinterpret_cast<const float4*>(qbase)[t];
    if (t < 48) qc[t / 3][t % 3] = coord[((size_t)b * N_ + n0 + t / 3) * 3 + (t % 3)];
    const double w4hd = (double)W_pos[h * 4 + 3];
    const double ghd  = 1.0 / (1.0 + exp(-(double)gating[h]));

    double sp[4], sq[4], spv[4], sqv[4];
    float accp[4], accq[4];
    #pragma unroll
    for (int i = 0; i < 4; ++i) {
        sp[i] = 0.0; sq[i] = 0.0; spv[i] = 0.0; sqv[i] = 0.0;
        accp[i] = 0.f; accq[i] = 0.f;
    }

    for (int m0 = 0; m0 < N_; m0 += 64) {
        __syncthreads();  // protect Kt/Vt/pt/qt from previous iteration readers
        const float4* kb4 = reinterpret_cast<const float4*>(k + (((size_t)b * H_ + h) * N_ + m0) * HD_);
        const float4* vb4 = reinterpret_cast<const float4*>(v + (((size_t)b * H_ + h) * N_ + m0) * HD_);
        #pragma unroll
        for (int i = 0; i < 4; ++i) {
            int vix = t + i * 256;
            int r   = vix >> 4;   // 0..63
            int c4  = vix & 15;
            Kt4[r][c4 ^ (r & 15)] = kb4[vix];
            Vt4[r][c4 ^ (r & 15)] = vb4[vix];
        }
        const double cmx = (double)coord[((size_t)b * N_ + m0 + l) * 3 + 0];
        const double cmy = (double)coord[((size_t)b * N_ + m0 + l) * 3 + 1];
        const double cmz = (double)coord[((size_t)b * N_ + m0 + l) * 3 + 2];
        const double Vm  = Vall[((size_t)b * H_ + h) * N_ + m0 + l];   // exact
        __syncthreads();

        // ---- QK^T logits: rows r = w+4i, column m0+l (4-way split partials)
        float dotp[4][4];
        #pragma unroll
        for (int i = 0; i < 4; ++i)
            #pragma unroll
            for (int g = 0; g < 4; ++g) dotp[i][g] = 0.f;
        #pragma unroll
        for (int d4 = 0; d4 < 16; ++d4) {
            const float4 kt = Kt4[l][d4 ^ (l & 15)];
            const int g = d4 >> 2;
            #pragma unroll
            for (int i = 0; i < 4; ++i) {
                const float4 q4 = Qs4[w + 4 * i][d4];
                dotp[i][g] += kt.x * q4.x + kt.y * q4.y + kt.z * q4.z + kt.w * q4.w;
            }
        }

        // ---- weights + f64 S-path updates
        #pragma unroll
        for (int i = 0; i < 4; ++i) {
            const int r = w + 4 * i;
            const double lg = (((double)dotp[i][0] + (double)dotp[i][1]) +
                               ((double)dotp[i][2] + (double)dotp[i][3])) * 0.125;
            const double p64 = exp(lg);
            const double dx = (double)qc[r][0] - cmx;
            const double dy = (double)qc[r][1] - cmy;
            const double dz = (double)qc[r][2] - cmz;
            const double q64 = exp(sqrt(dx * dx + dy * dy + dz * dz) * w4hd);
            pt[r][l] = (float)p64;
            qt[r][l] = (float)q64;
            sp[i]  += p64;
            sq[i]  += q64;
            spv[i] += p64 * Vm;
            sqv[i] += q64 * Vm;
        }
        __syncthreads();

        // ---- PV (f32, damped path): rows r = w+4i, output dim d = l
        const float* VtF = reinterpret_cast<const float*>(&Vt4[0][0]);
        #pragma unroll
        for (int ml4 = 0; ml4 < 16; ++ml4) {
            float vt[4];
            #pragma unroll
            for (int qq = 0; qq < 4; ++qq) {
                int ml = ml4 * 4 + qq;
                vt[qq] = VtF[ml * 64 + (((l >> 2) ^ (ml & 15)) << 2) + (l & 3)];
            }
            #pragma unroll
            for (int i = 0; i < 4; ++i) {
                const float4 pp = *reinterpret_cast<const float4*>(&pt[w + 4 * i][ml4 * 4]);
                const float4 pq = *reinterpret_cast<const float4*>(&qt[w + 4 * i][ml4 * 4]);
                accp[i] += pp.x * vt[0] + pp.y * vt[1] + pp.z * vt[2] + pp.w * vt[3];
                accq[i] += pq.x * vt[0] + pq.y * vt[1] + pq.z * vt[2] + pq.w * vt[3];
            }
        }
    }

    // ---- epilogue: f64 reduce, combine, normalize, store
    #pragma unroll
    for (int i = 0; i < 4; ++i) {
        double vsp = sp[i], vsq = sq[i], vspv = spv[i], vsqv = sqv[i];
        #pragma unroll
        for (int mm = 32; mm >= 1; mm >>= 1) {
            vsp  += __shfl_xor(vsp,  mm);
            vsq  += __shfl_xor(vsq,  mm);
            vspv += __shfl_xor(vspv, mm);
            vsqv += __shfl_xor(vsqv, mm);
        }
        const double w1 = (1.0 - ghd) / vsp;
        const double w2 = ghd / vsq;
        const double S  = w1 * vspv + w2 * vsqv;      // exact-path sum_d attn_d
        const double a  = w1 * (double)accp[i] + w2 * (double)accq[i];
        attn_out[((size_t)b * N_ + n0 + (w + 4 * i)) * C_ + h * HD_ + l] = (float)(a / S);
    }
}

// ---------------------------------------------------------------------------
extern "C" void kernel_launch(void* const* d_in, const int* in_sizes, int n_in,
                              void* d_out, int out_size, void* d_ws, size_t ws_size,
                              hipStream_t stream)
{
    const float* x      = (const float*)d_in[0];
    const float* coord  = (const float*)d_in[1];
    const float* W_qk   = (const float*)d_in[2];
    const float* W_v    = (const float*)d_in[3];
    const float* W_proj = (const float*)d_in[4];
    const float* b_proj = (const float*)d_in[5];
    const float* W_pos  = (const float*)d_in[6];
    // d_in[7] = b_pos (cancels in softmax), d_in[9] = pos_emb (cancels) — unused
    const float* gating = (const float*)d_in[8];

    float* ws   = (float*)d_ws;
    const size_t per = (size_t)B_ * H_ * N_ * HD_;   // 4,194,304 floats
    float*  qb   = ws;
    float*  kb   = qb + per;
    float*  vb   = kb + per;
    float*  attn = vb + per;
    double* wsh  = (double*)(attn + per);            // 16K doubles
    double* Vall = wsh + (size_t)H_ * C_;            // 64K doubles
    float*  out  = (float*)d_out;

    // 0) exact S-path precomputation
    wsum_kernel<<<dim3(4, 16), 256, 0, stream>>>(W_v, wsh);
    vall_kernel<<<dim3(4, 16, 4), 256, 0, stream>>>(x, wsh, Vall);

    // 1) fused QKV projection (slab-compensated f64 accumulation)
    gemm_kernel<0><<<dim3(48, 32), 256, 0, stream>>>(
        x, W_qk, W_v, nullptr, qb, kb, vb, B_ * N_, 3 * C_, C_);

    // 2) fused dual-softmax attention
    attn_kernel<<<dim3(N_ / 16, H_, B_), 256, 0, stream>>>(
        qb, kb, vb, Vall, coord, W_pos, gating, attn);

    // 3) output projection + bias
    gemm_kernel<1><<<dim3(16, 32), 256, 0, stream>>>(
        attn, W_proj, nullptr, b_proj, out, nullptr, nullptr, B_ * N_, C_, C_);
}